// Round 1
// baseline (376.527 us; speedup 1.0000x reference)
//
#include <hip/hip_runtime.h>

#define M_DIM 32
#define K_DIM 4096
#define N_DIM 16384

using short8 = __attribute__((ext_vector_type(8))) short;
using f32x4  = __attribute__((ext_vector_type(4))) float;

__device__ __forceinline__ ushort f2bf_rne(float f) {
    unsigned u = __float_as_uint(f);
    u += 0x7fffu + ((u >> 16) & 1u);
    return (ushort)(u >> 16);
}

// Exact for integers |v| <= 256: value fits in 8 significand bits, so the low
// 16 bits of the f32 encoding are zero and truncation to bf16 is lossless.
__device__ __forceinline__ ushort i2bf_exact(int v) {
    return (ushort)(__float_as_uint((float)v) >> 16);
}

__global__ __launch_bounds__(256) void prep_x_kernel(const float* __restrict__ x,
                                                     ushort* __restrict__ xb) {
    int i = blockIdx.x * blockDim.x + threadIdx.x;   // 32768 threads x 4 elems
    float4 v = reinterpret_cast<const float4*>(x)[i];
    ushort4 o;
    o.x = f2bf_rne(v.x); o.y = f2bf_rne(v.y); o.z = f2bf_rne(v.z); o.w = f2bf_rne(v.w);
    reinterpret_cast<ushort4*>(xb)[i] = o;
}

__global__ __launch_bounds__(256, 4) void qgemm_kernel(
        const ushort* __restrict__ xb, const int* __restrict__ wq,
        const int* __restrict__ zerop, const float* __restrict__ scalep,
        const float* __restrict__ bias, float* __restrict__ out) {
    const int n0   = blockIdx.x << 4;      // 16 output columns per block
    const int wave = threadIdx.x >> 6;     // 0..3 = K-split index
    const int lane = threadIdx.x & 63;
    const int quad = lane >> 4;
    const int l16  = lane & 15;
    const int zero = *zerop;

    const int k0 = wave << 10;             // 1024-wide K chunk per wave

    // A-fragment: lane holds x[m = l16][k = k0 + quad*8 + j], j=0..7 (bf16x8)
    const ushort* ap0 = xb + (size_t)l16 * K_DIM + k0 + (quad << 3);
    const ushort* ap1 = ap0 + 16 * K_DIM;  // second M-tile (rows 16..31)
    // B-fragment: lane holds W[n = n0 + l16][k = k0 + quad*8 + j] (int32 codes)
    const int* bp = wq + (size_t)(n0 + l16) * K_DIM + k0 + (quad << 3);

    f32x4 acc0 = {0.f, 0.f, 0.f, 0.f};
    f32x4 acc1 = {0.f, 0.f, 0.f, 0.f};

    #pragma unroll 4
    for (int ks = 0; ks < 32; ++ks) {
        short8 a0 = *reinterpret_cast<const short8*>(ap0);
        short8 a1 = *reinterpret_cast<const short8*>(ap1);
        int4 b0 = *reinterpret_cast<const int4*>(bp);
        int4 b1 = *reinterpret_cast<const int4*>(bp + 4);

        short8 bf;
        bf[0] = (short)i2bf_exact(b0.x - zero);
        bf[1] = (short)i2bf_exact(b0.y - zero);
        bf[2] = (short)i2bf_exact(b0.z - zero);
        bf[3] = (short)i2bf_exact(b0.w - zero);
        bf[4] = (short)i2bf_exact(b1.x - zero);
        bf[5] = (short)i2bf_exact(b1.y - zero);
        bf[6] = (short)i2bf_exact(b1.z - zero);
        bf[7] = (short)i2bf_exact(b1.w - zero);

        acc0 = __builtin_amdgcn_mfma_f32_16x16x32_bf16(a0, bf, acc0, 0, 0, 0);
        acc1 = __builtin_amdgcn_mfma_f32_16x16x32_bf16(a1, bf, acc1, 0, 0, 0);

        ap0 += 32; ap1 += 32; bp += 32;
    }

    // Split-K reduction through LDS (once per block; conflicts negligible).
    __shared__ float red[4][32][16];
    #pragma unroll
    for (int i = 0; i < 4; ++i) {
        red[wave][(quad << 2) + i][l16]      = acc0[i];  // C/D: row=quad*4+i, col=l16
        red[wave][16 + (quad << 2) + i][l16] = acc1[i];
    }
    __syncthreads();

    const float scale = *scalep;
    #pragma unroll
    for (int t = 0; t < 2; ++t) {
        int idx = threadIdx.x + (t << 8);   // 512 outputs, 256 threads
        int row = idx >> 4;
        int c   = idx & 15;
        float s = red[0][row][c] + red[1][row][c] + red[2][row][c] + red[3][row][c];
        out[(size_t)row * N_DIM + n0 + c] = fmaf(scale, s, bias[n0 + c]);
    }
}

extern "C" void kernel_launch(void* const* d_in, const int* in_sizes, int n_in,
                              void* d_out, int out_size, void* d_ws, size_t ws_size,
                              hipStream_t stream) {
    const float* x      = (const float*)d_in[0];
    const int*   wq     = (const int*)d_in[1];
    const int*   zerop  = (const int*)d_in[2];
    const float* scalep = (const float*)d_in[3];
    const float* bias   = (const float*)d_in[4];
    float*       out    = (float*)d_out;
    ushort*      xb     = (ushort*)d_ws;   // 32*4096 bf16 = 256 KB scratch

    prep_x_kernel<<<(M_DIM * K_DIM / 4) / 256, 256, 0, stream>>>(x, xb);
    qgemm_kernel<<<N_DIM / 16, 256, 0, stream>>>(xb, wq, zerop, scalep, bias, out);
}

// Round 3
// 359.873 us; speedup vs baseline: 1.0463x; 1.0463x over previous
//
#include <hip/hip_runtime.h>

#define M_DIM 32
#define K_DIM 4096
#define N_DIM 16384
#define BN 16          // weight rows per block
#define BK 128         // k per stage
#define NSTAGE 32      // K_DIM / BK
#define LROW 136       // ushorts per LDS row: 128 + 8 pad

using short8 = __attribute__((ext_vector_type(8))) short;
using f32x4  = __attribute__((ext_vector_type(4))) float;

__device__ __forceinline__ ushort f2bf_rne(float f) {
    unsigned u = __float_as_uint(f);
    u += 0x7fffu + ((u >> 16) & 1u);
    return (ushort)(u >> 16);
}

// Exact for integers |v| <= 256 (fits in 8 significand bits -> truncation lossless)
__device__ __forceinline__ ushort i2bf_exact(int v) {
    return (ushort)(__float_as_uint((float)v) >> 16);
}

__device__ __forceinline__ ushort4 cvt4(int4 v, int zero) {
    ushort4 o;
    o.x = i2bf_exact(v.x - zero);
    o.y = i2bf_exact(v.y - zero);
    o.z = i2bf_exact(v.z - zero);
    o.w = i2bf_exact(v.w - zero);
    return o;
}

__global__ __launch_bounds__(256) void prep_x_kernel(const float* __restrict__ x,
                                                     ushort* __restrict__ xb) {
    int i = blockIdx.x * blockDim.x + threadIdx.x;   // 32768 threads x 4 elems
    float4 v = reinterpret_cast<const float4*>(x)[i];
    ushort4 o;
    o.x = f2bf_rne(v.x); o.y = f2bf_rne(v.y); o.z = f2bf_rne(v.z); o.w = f2bf_rne(v.w);
    reinterpret_cast<ushort4*>(xb)[i] = o;
}

__global__ __launch_bounds__(256) void qgemm_kernel(
        const ushort* __restrict__ xb, const int* __restrict__ wq,
        const int* __restrict__ zerop, const float* __restrict__ scalep,
        const float* __restrict__ bias, float* __restrict__ out) {
    __shared__ ushort tile[BN][LROW];        // 4352 B, single stage buffer
    __shared__ float  red[4][M_DIM][BN];     // 8 KB, split-K reduction

    const int tid  = threadIdx.x;
    const int wave = tid >> 6;
    const int lane = tid & 63;
    const int quad = lane >> 4;
    const int l16  = lane & 15;
    const int n0   = blockIdx.x * BN;
    const int zero = *zerop;
    const int phase = blockIdx.x & (NSTAGE - 1);   // decorrelate k-phase across blocks

    // Staging: each half-wave reads one row's 128 contiguous ints (512 B run).
    // Thread covers rows wave*4 + (lane>>5) and +2, 16 B chunk at (lane&31)*16 B.
    const int srow0 = wave * 4 + (lane >> 5);
    const int srow1 = srow0 + 2;
    const int sofs  = (lane & 31) * 4;             // int (and ushort) index in row
    const int* gb0 = wq + (size_t)(n0 + srow0) * K_DIM + sofs;
    const int* gb1 = wq + (size_t)(n0 + srow1) * K_DIM + sofs;

    // A-fragment base: m = l16 (+16 for tile 1), k = stage*128 + wave*32 + quad*8
    const int bofs = wave * 32 + quad * 8;         // k-offset within a stage
    const ushort* axp0 = xb + (size_t)l16 * K_DIM + bofs;
    const ushort* axp1 = axp0 + 16 * K_DIM;

    f32x4 acc0 = {0.f, 0.f, 0.f, 0.f};
    f32x4 acc1 = {0.f, 0.f, 0.f, 0.f};

    // one-stage register prefetch
    int4 c0 = *(const int4*)(gb0 + phase * BK);
    int4 c1 = *(const int4*)(gb1 + phase * BK);

    #pragma unroll 1
    for (int s = 0; s < NSTAGE; ++s) {
        int4 nx0, nx1;
        if (s + 1 < NSTAGE) {                      // issue next stage's loads now;
            int sn = ((s + 1 + phase) & (NSTAGE - 1)) * BK;   // in flight across
            nx0 = *(const int4*)(gb0 + sn);        // barrier + LDS + MFMA below
            nx1 = *(const int4*)(gb1 + sn);
        }
        __syncthreads();                           // WAR: everyone done reading tile
        *(ushort4*)&tile[srow0][sofs] = cvt4(c0, zero);
        *(ushort4*)&tile[srow1][sofs] = cvt4(c1, zero);
        __syncthreads();                           // RAW: tile visible to all

        const int k0 = ((s + phase) & (NSTAGE - 1)) * BK;
        short8 a0 = *(const short8*)(axp0 + k0);
        short8 a1 = *(const short8*)(axp1 + k0);
        short8 bf = *(const short8*)&tile[l16][bofs];
        acc0 = __builtin_amdgcn_mfma_f32_16x16x32_bf16(a0, bf, acc0, 0, 0, 0);
        acc1 = __builtin_amdgcn_mfma_f32_16x16x32_bf16(a1, bf, acc1, 0, 0, 0);

        c0 = nx0; c1 = nx1;
    }

    // ---- split-K reduction (v1-verified layout: C row = quad*4+i, col = l16) ----
    __syncthreads();                               // done with tile before reusing LDS pressure
    #pragma unroll
    for (int i = 0; i < 4; ++i) {
        red[wave][(quad << 2) + i][l16]      = acc0[i];
        red[wave][16 + (quad << 2) + i][l16] = acc1[i];
    }
    __syncthreads();

    const float scale = *scalep;
    #pragma unroll
    for (int t = 0; t < 2; ++t) {
        int idx = tid + (t << 8);                  // 512 outputs, 256 threads
        int row = idx >> 4;
        int c   = idx & 15;
        float s = red[0][row][c] + red[1][row][c] + red[2][row][c] + red[3][row][c];
        out[(size_t)row * N_DIM + n0 + c] = fmaf(scale, s, bias[n0 + c]);
    }
}

extern "C" void kernel_launch(void* const* d_in, const int* in_sizes, int n_in,
                              void* d_out, int out_size, void* d_ws, size_t ws_size,
                              hipStream_t stream) {
    const float* x      = (const float*)d_in[0];
    const int*   wq     = (const int*)d_in[1];
    const int*   zerop  = (const int*)d_in[2];
    const float* scalep = (const float*)d_in[3];
    const float* bias   = (const float*)d_in[4];
    float*       out    = (float*)d_out;
    ushort*      xb     = (ushort*)d_ws;   // 32*4096 bf16 = 256 KB scratch (v1-proven)

    prep_x_kernel<<<(M_DIM * K_DIM / 4) / 256, 256, 0, stream>>>(x, xb);
    qgemm_kernel<<<N_DIM / BN, 256, 0, stream>>>(xb, wq, zerop, scalep, bias, out);
}